// Round 6
// baseline (224.103 us; speedup 1.0000x reference)
//
#include <hip/hip_runtime.h>
#include <math.h>

#define SL 2048   // sequence length L
#define NB 32     // batch
#define NH 128    // feature dim H
#define NP 256    // state dim P (complex)
#define NP2 512   // interleaved real/imag columns

typedef short bf16x8 __attribute__((ext_vector_type(8)));
typedef float f32x4  __attribute__((ext_vector_type(4)));

static __device__ __forceinline__ unsigned short f2bf(float x) {
    unsigned u = __float_as_uint(x);
    return (unsigned short)((u + 0x7fffu + ((u >> 16) & 1u)) >> 16);  // RNE
}
static __device__ __forceinline__ float bf2f(unsigned short h) {
    return __uint_as_float(((unsigned)h) << 16);
}
static __device__ __forceinline__ void discretize(
    const float* __restrict__ logLr, const float* __restrict__ Lim,
    const float* __restrict__ logDt, int p, float& wr, float& wi)
{
    const float Lr = expf(logLr[p]);
    const float dt = expf(logDt[p]);
    const float ew = expf(-Lr * dt);
    const float ang = Lim[p] * dt;
    wr = ew * cosf(ang); wi = ew * sinf(ang);
}

// XOR-swizzled LDS index: 4-uint blocks, blk' = blk ^ (row & 15).
// Conflict-free (<=2-way) for: GEMM1 uint2 stores, per-column scan, b128 reads.
static __device__ __forceinline__ int xsidx(int row, int p) {
    return row * 256 + ((((p >> 2) ^ (row & 15))) << 2) + (p & 3);
}

// ---------------------------------------------------------------------------
// k0: pack Bhat[p'=512][h=128] = f_p * B_tilde and Chat[h=128][p'=512] =
// [Cr, -Ci] interleaved, both bf16.
// ---------------------------------------------------------------------------
__global__ __launch_bounds__(256) void k0(
    const float* __restrict__ logLr, const float* __restrict__ Lim,
    const float* __restrict__ logDt,
    const float* __restrict__ Br, const float* __restrict__ Bi,
    const float* __restrict__ Cr, const float* __restrict__ Ci,
    unsigned short* __restrict__ Bhat, unsigned short* __restrict__ Chat)
{
    const int tid = blockIdx.x * 256 + threadIdx.x;  // 32768 = P*H
    const int p = tid >> 7, h = tid & 127;
    float wr, wi; discretize(logLr, Lim, logDt, p, wr, wi);
    const float Lr = expf(logLr[p]), li = Lim[p];
    const float nr = wr - 1.0f, ni = wi;
    const float den = Lr * Lr + li * li;
    const float fr = (-nr * Lr + ni * li) / den;
    const float fi = (-ni * Lr - nr * li) / den;
    const float br = Br[p * NH + h], bi = Bi[p * NH + h];
    Bhat[(size_t)(2 * p)     * NH + h] = f2bf(fr * br - fi * bi);
    Bhat[(size_t)(2 * p + 1) * NH + h] = f2bf(fr * bi + fi * br);
    Chat[(size_t)h * NP2 + 2 * p]     = f2bf(Cr[h * NP + p]);
    Chat[(size_t)h * NP2 + 2 * p + 1] = f2bf(-Ci[h * NP + p]);
}

// ---------------------------------------------------------------------------
// gA: carry pass. One block per (32-l tile, b). GEMM1 tile -> swizzled LDS,
// in-LDS carry scan, emit part[b][tile][p] = sum_k w^(31-k) x[k]. No bu.
// ---------------------------------------------------------------------------
__global__ __launch_bounds__(256, 2) void gA(
    const float* __restrict__ u, const unsigned short* __restrict__ Bhat,
    const float* __restrict__ logLr, const float* __restrict__ Lim,
    const float* __restrict__ logDt, float2* __restrict__ part)
{
    __shared__ unsigned short us[32][136];   // u tile bf16 [l][h], pad 8
    __shared__ unsigned xs[32 * 256];        // GEMM1 tile, swizzled (32 KB)

    const int tile = blockIdx.x;             // 0..63
    const int b    = blockIdx.y;
    const int l0   = tile * 32;
    const int tid  = threadIdx.x;
    const int wave = tid >> 6, lane = tid & 63;
    const int q = lane >> 4, c = lane & 15;
    const int pbase = wave * 128;

    {   // stage u tile (32 l x 128 h) fp32 -> bf16 LDS
        const int lrow = tid >> 3;
        const int hcol = (tid & 7) * 16;
        const float* up = u + (size_t)(l0 + lrow) * (NB * NH) + b * NH + hcol;
        float4 a = *(const float4*)(up + 0);
        float4 d = *(const float4*)(up + 4);
        float4 e = *(const float4*)(up + 8);
        float4 g = *(const float4*)(up + 12);
        uint4 w0, w1;
        w0.x = (unsigned)f2bf(a.x) | ((unsigned)f2bf(a.y) << 16);
        w0.y = (unsigned)f2bf(a.z) | ((unsigned)f2bf(a.w) << 16);
        w0.z = (unsigned)f2bf(d.x) | ((unsigned)f2bf(d.y) << 16);
        w0.w = (unsigned)f2bf(d.z) | ((unsigned)f2bf(d.w) << 16);
        w1.x = (unsigned)f2bf(e.x) | ((unsigned)f2bf(e.y) << 16);
        w1.y = (unsigned)f2bf(e.z) | ((unsigned)f2bf(e.w) << 16);
        w1.z = (unsigned)f2bf(g.x) | ((unsigned)f2bf(g.y) << 16);
        w1.w = (unsigned)f2bf(g.z) | ((unsigned)f2bf(g.w) << 16);
        *(uint4*)&us[lrow][hcol + 0] = w0;
        *(uint4*)&us[lrow][hcol + 8] = w1;
    }
    __syncthreads();

    f32x4 acc[8][2];
    #pragma unroll
    for (int mt = 0; mt < 8; ++mt)
        #pragma unroll
        for (int nt = 0; nt < 2; ++nt) acc[mt][nt] = (f32x4){0.f, 0.f, 0.f, 0.f};

    #pragma unroll
    for (int kk = 0; kk < 4; ++kk) {
        bf16x8 af[8];
        #pragma unroll
        for (int mt = 0; mt < 8; ++mt)
            af[mt] = *(const bf16x8*)(Bhat + (size_t)(pbase + 16 * mt + c) * NH
                                           + kk * 32 + 8 * q);
        bf16x8 bfr[2];
        #pragma unroll
        for (int nt = 0; nt < 2; ++nt)
            bfr[nt] = *(const bf16x8*)&us[16 * nt + c][kk * 32 + 8 * q];
        #pragma unroll
        for (int mt = 0; mt < 8; ++mt)
            #pragma unroll
            for (int nt = 0; nt < 2; ++nt)
                acc[mt][nt] = __builtin_amdgcn_mfma_f32_16x16x32_bf16(
                    af[mt], bfr[nt], acc[mt][nt], 0, 0, 0);
    }

    // stash to swizzled xs (bf16 pairs)
    #pragma unroll
    for (int mt = 0; mt < 8; ++mt)
        #pragma unroll
        for (int nt = 0; nt < 2; ++nt) {
            const int rw  = 16 * nt + c;                      // rw & 15 == c
            const int col = (pbase + 16 * mt + 4 * q) >> 1;   // complex col
            const int idx = rw * 256 + (((col >> 2) ^ c) << 2) + (col & 3);
            uint2 pk;
            pk.x = (unsigned)f2bf(acc[mt][nt][0]) | ((unsigned)f2bf(acc[mt][nt][1]) << 16);
            pk.y = (unsigned)f2bf(acc[mt][nt][2]) | ((unsigned)f2bf(acc[mt][nt][3]) << 16);
            *(uint2*)&xs[idx] = pk;
        }
    __syncthreads();

    // carry-only scan of column p = tid over 32 rows
    {
        const int p = tid;
        float wr, wi; discretize(logLr, Lim, logDt, p, wr, wi);
        float sr = 0.f, si = 0.f;
        unsigned va[8], vb[8];
        #pragma unroll
        for (int j = 0; j < 8; ++j) va[j] = xs[xsidx(j, p)];
        #pragma unroll
        for (int k8 = 0; k8 < 4; ++k8) {
            if (k8 < 3) {
                #pragma unroll
                for (int j = 0; j < 8; ++j) vb[j] = xs[xsidx((k8 + 1) * 8 + j, p)];
            }
            #pragma unroll
            for (int j = 0; j < 8; ++j) {
                const float xr = bf2f((unsigned short)(va[j] & 0xffffu));
                const float xi = bf2f((unsigned short)(va[j] >> 16));
                const float tr = wr * sr - wi * si + xr;
                const float ti = wr * si + wi * sr + xi;
                sr = tr; si = ti;
            }
            #pragma unroll
            for (int j = 0; j < 8; ++j) va[j] = vb[j];
        }
        part[((size_t)b * 64 + tile) * NP + p] = make_float2(sr, si);
    }
}

// ---------------------------------------------------------------------------
// s2: scan 32-l chunk carries -> state ENTERING each chunk (w^32 composition).
// ---------------------------------------------------------------------------
__global__ __launch_bounds__(256) void s2(
    const float2* __restrict__ part, const float* __restrict__ logLr,
    const float* __restrict__ Lim, const float* __restrict__ logDt,
    float2* __restrict__ C)
{
    const int b = blockIdx.x, p = threadIdx.x;
    float wr, wi; discretize(logLr, Lim, logDt, p, wr, wi);
    float Wr = wr, Wi = wi;
    #pragma unroll
    for (int t = 0; t < 5; ++t) { const float r = Wr * Wr - Wi * Wi; Wi = 2.f * Wr * Wi; Wr = r; }  // w^32
    float sr = 0.f, si = 0.f;
    for (int m = 0; m < 64; ++m) {
        C[(size_t)(b * 64 + m) * NP + p] = make_float2(sr, si);
        const float2 v = part[(size_t)(b * 64 + m) * NP + p];
        const float tr = Wr * sr - Wi * si + v.x;
        const float ti = Wr * si + Wi * sr + v.y;
        sr = tr; si = ti;
    }
}

// ---------------------------------------------------------------------------
// gC: recompute GEMM1 (64-l tile, u direct from global/L3, Bhat from L2),
// scan in LDS (two interleaved independent 32-l chains from precomputed
// entering states), GEMM2 from LDS, +D.*u epilogue. o never hits HBM.
// LDS: exactly 64 KB swizzled.
// ---------------------------------------------------------------------------
__global__ __launch_bounds__(256, 2) void gC(
    const float* __restrict__ u, const unsigned short* __restrict__ Bhat,
    const unsigned short* __restrict__ Chat,
    const float* __restrict__ logLr, const float* __restrict__ Lim,
    const float* __restrict__ logDt, const float2* __restrict__ C,
    const float* __restrict__ Dv, float* __restrict__ out)
{
    __shared__ unsigned xs[64 * 256];   // 65536 B

    const int m = blockIdx.x;            // 64-l tile, 0..31
    const int b = blockIdx.y;
    const int tid = threadIdx.x;
    const int wave = tid >> 6, lane = tid & 63;
    const int q = lane >> 4, c = lane & 15;
    const int pbase = wave * 128;

    // ---- GEMM1 recompute: two 32-l halves ----
    #pragma unroll
    for (int half = 0; half < 2; ++half) {
        const int lt = m * 64 + half * 32;
        f32x4 acc[8][2];
        #pragma unroll
        for (int mt = 0; mt < 8; ++mt)
            #pragma unroll
            for (int nt = 0; nt < 2; ++nt) acc[mt][nt] = (f32x4){0.f, 0.f, 0.f, 0.f};

        #pragma unroll
        for (int kk = 0; kk < 4; ++kk) {
            bf16x8 af[8];
            #pragma unroll
            for (int mt = 0; mt < 8; ++mt)
                af[mt] = *(const bf16x8*)(Bhat + (size_t)(pbase + 16 * mt + c) * NH
                                               + kk * 32 + 8 * q);
            bf16x8 bfr[2];
            #pragma unroll
            for (int nt = 0; nt < 2; ++nt) {
                const float* up = u + (size_t)(lt + 16 * nt + c) * (NB * NH)
                                    + b * NH + kk * 32 + 8 * q;
                float4 x = *(const float4*)up;
                float4 y = *(const float4*)(up + 4);
                bf16x8 t;
                t[0] = (short)f2bf(x.x); t[1] = (short)f2bf(x.y);
                t[2] = (short)f2bf(x.z); t[3] = (short)f2bf(x.w);
                t[4] = (short)f2bf(y.x); t[5] = (short)f2bf(y.y);
                t[6] = (short)f2bf(y.z); t[7] = (short)f2bf(y.w);
                bfr[nt] = t;
            }
            #pragma unroll
            for (int mt = 0; mt < 8; ++mt)
                #pragma unroll
                for (int nt = 0; nt < 2; ++nt)
                    acc[mt][nt] = __builtin_amdgcn_mfma_f32_16x16x32_bf16(
                        af[mt], bfr[nt], acc[mt][nt], 0, 0, 0);
        }

        #pragma unroll
        for (int mt = 0; mt < 8; ++mt)
            #pragma unroll
            for (int nt = 0; nt < 2; ++nt) {
                const int rw  = half * 32 + 16 * nt + c;          // rw & 15 == c
                const int col = (pbase + 16 * mt + 4 * q) >> 1;
                const int idx = rw * 256 + (((col >> 2) ^ c) << 2) + (col & 3);
                uint2 pk;
                pk.x = (unsigned)f2bf(acc[mt][nt][0]) | ((unsigned)f2bf(acc[mt][nt][1]) << 16);
                pk.y = (unsigned)f2bf(acc[mt][nt][2]) | ((unsigned)f2bf(acc[mt][nt][3]) << 16);
                *(uint2*)&xs[idx] = pk;
            }
    }
    __syncthreads();

    // ---- scan: two independent 32-l chains, interleaved for ILP ----
    {
        const int p = tid;
        float wr, wi; discretize(logLr, Lim, logDt, p, wr, wi);
        const float2 E0 = C[(size_t)(b * 64 + 2 * m)     * NP + p];
        const float2 E1 = C[(size_t)(b * 64 + 2 * m + 1) * NP + p];
        float s0r = E0.x, s0i = E0.y;
        float s1r = E1.x, s1i = E1.y;
        #pragma unroll
        for (int k = 0; k < 32; ++k) {
            const int i0 = xsidx(k, p);
            const int i1 = xsidx(32 + k, p);
            const unsigned v0 = xs[i0];
            const unsigned v1 = xs[i1];
            {
                const float xr = bf2f((unsigned short)(v0 & 0xffffu));
                const float xi = bf2f((unsigned short)(v0 >> 16));
                const float tr = wr * s0r - wi * s0i + xr;
                const float ti = wr * s0i + wi * s0r + xi;
                s0r = tr; s0i = ti;
                xs[i0] = (unsigned)f2bf(tr) | ((unsigned)f2bf(ti) << 16);
            }
            {
                const float xr = bf2f((unsigned short)(v1 & 0xffffu));
                const float xi = bf2f((unsigned short)(v1 >> 16));
                const float tr = wr * s1r - wi * s1i + xr;
                const float ti = wr * s1i + wi * s1r + xi;
                s1r = tr; s1i = ti;
                xs[i1] = (unsigned)f2bf(tr) | ((unsigned)f2bf(ti) << 16);
            }
        }
    }
    __syncthreads();

    // ---- GEMM2 from LDS ----
    const int wm = wave >> 1, wn = wave & 1;
    const int hbase = wm * 64, lloc = wn * 32;

    f32x4 acc[4][2];
    #pragma unroll
    for (int mt = 0; mt < 4; ++mt)
        #pragma unroll
        for (int nt = 0; nt < 2; ++nt) acc[mt][nt] = (f32x4){0.f, 0.f, 0.f, 0.f};

    #pragma unroll 4
    for (int kk = 0; kk < 16; ++kk) {
        bf16x8 af[4];
        #pragma unroll
        for (int mt = 0; mt < 4; ++mt)
            af[mt] = *(const bf16x8*)(Chat + (size_t)(hbase + 16 * mt + c) * NP2
                                           + kk * 32 + 8 * q);
        bf16x8 bfr[2];
        #pragma unroll
        for (int nt = 0; nt < 2; ++nt) {
            const int rw = lloc + 16 * nt + c;                // rw & 15 == c
            bfr[nt] = *(const bf16x8*)&xs[rw * 256 + (((4 * kk + q) ^ c) << 2)];
        }
        #pragma unroll
        for (int mt = 0; mt < 4; ++mt)
            #pragma unroll
            for (int nt = 0; nt < 2; ++nt)
                acc[mt][nt] = __builtin_amdgcn_mfma_f32_16x16x32_bf16(
                    af[mt], bfr[nt], acc[mt][nt], 0, 0, 0);
    }

    #pragma unroll
    for (int mt = 0; mt < 4; ++mt) {
        const int h4 = hbase + 16 * mt + 4 * q;
        const float4 dd = *(const float4*)(Dv + h4);
        #pragma unroll
        for (int nt = 0; nt < 2; ++nt) {
            const int l = m * 64 + lloc + 16 * nt + c;
            const size_t off = ((size_t)l * NB + b) * NH + h4;
            const float4 uu = *(const float4*)(u + off);
            float4 ov;
            ov.x = acc[mt][nt][0] + dd.x * uu.x;
            ov.y = acc[mt][nt][1] + dd.y * uu.y;
            ov.z = acc[mt][nt][2] + dd.z * uu.z;
            ov.w = acc[mt][nt][3] + dd.w * uu.w;
            *(float4*)(out + off) = ov;
        }
    }
}

extern "C" void kernel_launch(void* const* d_in, const int* in_sizes, int n_in,
                              void* d_out, int out_size, void* d_ws, size_t ws_size,
                              hipStream_t stream)
{
    const float* u     = (const float*)d_in[0];
    const float* logLr = (const float*)d_in[1];
    const float* Lim   = (const float*)d_in[2];
    const float* Btr   = (const float*)d_in[3];
    const float* Bti   = (const float*)d_in[4];
    const float* Ctr   = (const float*)d_in[5];
    const float* Cti   = (const float*)d_in[6];
    const float* Dv    = (const float*)d_in[7];
    const float* logDt = (const float*)d_in[8];
    float* out = (float*)d_out;

    char* ws = (char*)d_ws;
    float2*         part = (float2*)ws;                        // 4,194,304 B (32*64*256)
    float2*         Cst  = (float2*)(ws + 4194304);            // 4,194,304 B
    unsigned short* Bhat = (unsigned short*)(ws + 8388608);    //   131,072 B
    unsigned short* Chat = (unsigned short*)(ws + 8519680);    //   131,072 B

    k0<<<dim3((NP * NH) / 256), 256, 0, stream>>>(logLr, Lim, logDt,
                                                  Btr, Bti, Ctr, Cti, Bhat, Chat);
    gA<<<dim3(SL / 32, NB), 256, 0, stream>>>(u, Bhat, logLr, Lim, logDt, part);
    s2<<<dim3(NB), 256, 0, stream>>>(part, logLr, Lim, logDt, Cst);
    gC<<<dim3(SL / 64, NB), 256, 0, stream>>>(u, Bhat, Chat, logLr, Lim, logDt,
                                              Cst, Dv, out);
}

// Round 7
// 223.581 us; speedup vs baseline: 1.0023x; 1.0023x over previous
//
#include <hip/hip_runtime.h>
#include <math.h>

#define SL 2048   // sequence length L
#define NB 32     // batch
#define NH 128    // feature dim H
#define NP 256    // state dim P (complex)
#define NP2 512   // interleaved real/imag columns

typedef short bf16x8 __attribute__((ext_vector_type(8)));
typedef float f32x4  __attribute__((ext_vector_type(4)));

static __device__ __forceinline__ unsigned short f2bf(float x) {
    unsigned u = __float_as_uint(x);
    return (unsigned short)((u + 0x7fffu + ((u >> 16) & 1u)) >> 16);  // RNE
}
static __device__ __forceinline__ float bf2f(unsigned short h) {
    return __uint_as_float(((unsigned)h) << 16);
}
static __device__ __forceinline__ void discretize(
    const float* __restrict__ logLr, const float* __restrict__ Lim,
    const float* __restrict__ logDt, int p, float& wr, float& wi)
{
    const float Lr = expf(logLr[p]);
    const float dt = expf(logDt[p]);
    const float ew = expf(-Lr * dt);
    const float ang = Lim[p] * dt;
    wr = ew * cosf(ang); wi = ew * sinf(ang);
}

// XOR-swizzled LDS index for the 32-l x 256-complex tile (32 KB).
// bank(row,p) is <=2-way for: uint2 acc stores, per-column scan, b128 reads.
static __device__ __forceinline__ int xsidx(int row, int p) {
    return row * 256 + ((((p >> 2) ^ (row & 15))) << 2) + (p & 3);
}

// ---------------------------------------------------------------------------
// k0: pack Bhat[p'=512][h=128] = f_p * B_tilde and Chat[h=128][p'=512] =
// [Cr, -Ci] interleaved, both bf16.
// ---------------------------------------------------------------------------
__global__ __launch_bounds__(256) void k0(
    const float* __restrict__ logLr, const float* __restrict__ Lim,
    const float* __restrict__ logDt,
    const float* __restrict__ Br, const float* __restrict__ Bi,
    const float* __restrict__ Cr, const float* __restrict__ Ci,
    unsigned short* __restrict__ Bhat, unsigned short* __restrict__ Chat)
{
    const int tid = blockIdx.x * 256 + threadIdx.x;  // 32768 = P*H
    const int p = tid >> 7, h = tid & 127;
    float wr, wi; discretize(logLr, Lim, logDt, p, wr, wi);
    const float Lr = expf(logLr[p]), li = Lim[p];
    const float nr = wr - 1.0f, ni = wi;
    const float den = Lr * Lr + li * li;
    const float fr = (-nr * Lr + ni * li) / den;
    const float fi = (-ni * Lr - nr * li) / den;
    const float br = Br[p * NH + h], bi = Bi[p * NH + h];
    Bhat[(size_t)(2 * p)     * NH + h] = f2bf(fr * br - fi * bi);
    Bhat[(size_t)(2 * p + 1) * NH + h] = f2bf(fr * bi + fi * br);
    Chat[(size_t)h * NP2 + 2 * p]     = f2bf(Cr[h * NP + p]);
    Chat[(size_t)h * NP2 + 2 * p + 1] = f2bf(-Ci[h * NP + p]);
}

// ---------------------------------------------------------------------------
// GEMM1 for a 32-l tile -> swizzled xs. u fragments read per-lane direct
// from global (fp32 -> bf16 in-reg); Bhat A-frags from L2.
// ---------------------------------------------------------------------------
static __device__ __forceinline__ void gemm1_tile(
    const float* __restrict__ u, const unsigned short* __restrict__ Bhat,
    unsigned* xs, int b, int l0, int tid)
{
    const int wave = tid >> 6, lane = tid & 63;
    const int q = lane >> 4, c = lane & 15;
    const int pbase = wave * 128;

    f32x4 acc[8][2];
    #pragma unroll
    for (int mt = 0; mt < 8; ++mt)
        #pragma unroll
        for (int nt = 0; nt < 2; ++nt) acc[mt][nt] = (f32x4){0.f, 0.f, 0.f, 0.f};

    #pragma unroll
    for (int kk = 0; kk < 4; ++kk) {
        bf16x8 af[8];
        #pragma unroll
        for (int mt = 0; mt < 8; ++mt)
            af[mt] = *(const bf16x8*)(Bhat + (size_t)(pbase + 16 * mt + c) * NH
                                           + kk * 32 + 8 * q);
        bf16x8 bfr[2];
        #pragma unroll
        for (int nt = 0; nt < 2; ++nt) {
            const float* up = u + (size_t)(l0 + 16 * nt + c) * (NB * NH)
                                + b * NH + kk * 32 + 8 * q;
            float4 x = *(const float4*)up;
            float4 y = *(const float4*)(up + 4);
            bf16x8 t;
            t[0] = (short)f2bf(x.x); t[1] = (short)f2bf(x.y);
            t[2] = (short)f2bf(x.z); t[3] = (short)f2bf(x.w);
            t[4] = (short)f2bf(y.x); t[5] = (short)f2bf(y.y);
            t[6] = (short)f2bf(y.z); t[7] = (short)f2bf(y.w);
            bfr[nt] = t;
        }
        #pragma unroll
        for (int mt = 0; mt < 8; ++mt)
            #pragma unroll
            for (int nt = 0; nt < 2; ++nt)
                acc[mt][nt] = __builtin_amdgcn_mfma_f32_16x16x32_bf16(
                    af[mt], bfr[nt], acc[mt][nt], 0, 0, 0);
    }

    #pragma unroll
    for (int mt = 0; mt < 8; ++mt)
        #pragma unroll
        for (int nt = 0; nt < 2; ++nt) {
            const int rw  = 16 * nt + c;                      // rw & 15 == c
            const int col = (pbase + 16 * mt + 4 * q) >> 1;   // complex col
            const int idx = rw * 256 + (((col >> 2) ^ c) << 2) + (col & 3);
            uint2 pk;
            pk.x = (unsigned)f2bf(acc[mt][nt][0]) | ((unsigned)f2bf(acc[mt][nt][1]) << 16);
            pk.y = (unsigned)f2bf(acc[mt][nt][2]) | ((unsigned)f2bf(acc[mt][nt][3]) << 16);
            *(uint2*)&xs[idx] = pk;
        }
}

// ---------------------------------------------------------------------------
// gA: carry pass. One block per (32-l tile, b): GEMM1 -> xs, in-LDS carry
// scan, part[b][tile][p] = sum_k w^(31-k) x[k].   LDS = 32 KB.
// ---------------------------------------------------------------------------
__global__ __launch_bounds__(256, 4) void gA(
    const float* __restrict__ u, const unsigned short* __restrict__ Bhat,
    const float* __restrict__ logLr, const float* __restrict__ Lim,
    const float* __restrict__ logDt, float2* __restrict__ part)
{
    __shared__ unsigned xs[32 * 256];

    const int tile = blockIdx.x;             // 0..63
    const int b    = blockIdx.y;
    const int tid  = threadIdx.x;

    gemm1_tile(u, Bhat, xs, b, tile * 32, tid);
    __syncthreads();

    const int p = tid;
    float wr, wi; discretize(logLr, Lim, logDt, p, wr, wi);
    float sr = 0.f, si = 0.f;
    #pragma unroll
    for (int k = 0; k < 32; ++k) {
        const unsigned v = xs[xsidx(k, p)];
        const float xr = bf2f((unsigned short)(v & 0xffffu));
        const float xi = bf2f((unsigned short)(v >> 16));
        const float tr = wr * sr - wi * si + xr;
        const float ti = wr * si + wi * sr + xi;
        sr = tr; si = ti;
    }
    part[((size_t)b * 64 + tile) * NP + p] = make_float2(sr, si);
}

// ---------------------------------------------------------------------------
// s2: scan 32-l chunk carries -> state ENTERING each chunk (w^32 composition).
// ---------------------------------------------------------------------------
__global__ __launch_bounds__(256) void s2(
    const float2* __restrict__ part, const float* __restrict__ logLr,
    const float* __restrict__ Lim, const float* __restrict__ logDt,
    float2* __restrict__ C)
{
    const int b = blockIdx.x, p = threadIdx.x;
    float wr, wi; discretize(logLr, Lim, logDt, p, wr, wi);
    float Wr = wr, Wi = wi;
    #pragma unroll
    for (int t = 0; t < 5; ++t) { const float r = Wr * Wr - Wi * Wi; Wi = 2.f * Wr * Wi; Wr = r; }  // w^32
    float sr = 0.f, si = 0.f;
    for (int m = 0; m < 64; ++m) {
        C[(size_t)(b * 64 + m) * NP + p] = make_float2(sr, si);
        const float2 v = part[(size_t)(b * 64 + m) * NP + p];
        const float tr = Wr * sr - Wi * si + v.x;
        const float ti = Wr * si + Wi * sr + v.y;
        sr = tr; si = ti;
    }
}

// ---------------------------------------------------------------------------
// gC: one block per (32-l tile, b). Recompute GEMM1 -> xs, scan-writeback
// from the precomputed entering state, GEMM2 from LDS, +D.*u epilogue.
// LDS = 32 KB -> 4 blocks/CU.
// ---------------------------------------------------------------------------
__global__ __launch_bounds__(256, 4) void gC(
    const float* __restrict__ u, const unsigned short* __restrict__ Bhat,
    const unsigned short* __restrict__ Chat,
    const float* __restrict__ logLr, const float* __restrict__ Lim,
    const float* __restrict__ logDt, const float2* __restrict__ C,
    const float* __restrict__ Dv, float* __restrict__ out)
{
    __shared__ unsigned xs[32 * 256];

    const int m = blockIdx.x;            // 32-l tile, 0..63
    const int b = blockIdx.y;
    const int tid = threadIdx.x;
    const int wave = tid >> 6, lane = tid & 63;
    const int q = lane >> 4, c = lane & 15;

    gemm1_tile(u, Bhat, xs, b, m * 32, tid);
    __syncthreads();

    // ---- scan-writeback from entering state ----
    {
        const int p = tid;
        float wr, wi; discretize(logLr, Lim, logDt, p, wr, wi);
        const float2 E = C[(size_t)(b * 64 + m) * NP + p];
        float sr = E.x, si = E.y;
        #pragma unroll
        for (int k = 0; k < 32; ++k) {
            const int idx = xsidx(k, p);
            const unsigned v = xs[idx];
            const float xr = bf2f((unsigned short)(v & 0xffffu));
            const float xi = bf2f((unsigned short)(v >> 16));
            const float tr = wr * sr - wi * si + xr;
            const float ti = wr * si + wi * sr + xi;
            sr = tr; si = ti;
            xs[idx] = (unsigned)f2bf(tr) | ((unsigned)f2bf(ti) << 16);
        }
    }
    __syncthreads();

    // ---- GEMM2 from LDS: out[32 l][128 h]; wave owns 32 h ----
    const int hbase = wave * 32;

    f32x4 acc[2][2];
    #pragma unroll
    for (int mt = 0; mt < 2; ++mt)
        #pragma unroll
        for (int nt = 0; nt < 2; ++nt) acc[mt][nt] = (f32x4){0.f, 0.f, 0.f, 0.f};

    #pragma unroll 4
    for (int kk = 0; kk < 16; ++kk) {
        bf16x8 af[2];
        #pragma unroll
        for (int mt = 0; mt < 2; ++mt)
            af[mt] = *(const bf16x8*)(Chat + (size_t)(hbase + 16 * mt + c) * NP2
                                           + kk * 32 + 8 * q);
        bf16x8 bfr[2];
        #pragma unroll
        for (int nt = 0; nt < 2; ++nt) {
            const int rw = 16 * nt + c;                       // rw & 15 == c
            bfr[nt] = *(const bf16x8*)&xs[rw * 256 + (((4 * kk + q) ^ c) << 2)];
        }
        #pragma unroll
        for (int mt = 0; mt < 2; ++mt)
            #pragma unroll
            for (int nt = 0; nt < 2; ++nt)
                acc[mt][nt] = __builtin_amdgcn_mfma_f32_16x16x32_bf16(
                    af[mt], bfr[nt], acc[mt][nt], 0, 0, 0);
    }

    #pragma unroll
    for (int mt = 0; mt < 2; ++mt) {
        const int h4 = hbase + 16 * mt + 4 * q;
        const float4 dd = *(const float4*)(Dv + h4);
        #pragma unroll
        for (int nt = 0; nt < 2; ++nt) {
            const int l = m * 32 + 16 * nt + c;
            const size_t off = ((size_t)l * NB + b) * NH + h4;
            const float4 uu = *(const float4*)(u + off);
            float4 ov;
            ov.x = acc[mt][nt][0] + dd.x * uu.x;
            ov.y = acc[mt][nt][1] + dd.y * uu.y;
            ov.z = acc[mt][nt][2] + dd.z * uu.z;
            ov.w = acc[mt][nt][3] + dd.w * uu.w;
            *(float4*)(out + off) = ov;
        }
    }
}

extern "C" void kernel_launch(void* const* d_in, const int* in_sizes, int n_in,
                              void* d_out, int out_size, void* d_ws, size_t ws_size,
                              hipStream_t stream)
{
    const float* u     = (const float*)d_in[0];
    const float* logLr = (const float*)d_in[1];
    const float* Lim   = (const float*)d_in[2];
    const float* Btr   = (const float*)d_in[3];
    const float* Bti   = (const float*)d_in[4];
    const float* Ctr   = (const float*)d_in[5];
    const float* Cti   = (const float*)d_in[6];
    const float* Dv    = (const float*)d_in[7];
    const float* logDt = (const float*)d_in[8];
    float* out = (float*)d_out;

    char* ws = (char*)d_ws;
    float2*         part = (float2*)ws;                        // 4,194,304 B (32*64*256)
    float2*         Cst  = (float2*)(ws + 4194304);            // 4,194,304 B
    unsigned short* Bhat = (unsigned short*)(ws + 8388608);    //   131,072 B
    unsigned short* Chat = (unsigned short*)(ws + 8519680);    //   131,072 B

    k0<<<dim3((NP * NH) / 256), 256, 0, stream>>>(logLr, Lim, logDt,
                                                  Btr, Bti, Ctr, Cti, Bhat, Chat);
    gA<<<dim3(SL / 32, NB), 256, 0, stream>>>(u, Bhat, logLr, Lim, logDt, part);
    s2<<<dim3(NB), 256, 0, stream>>>(part, logLr, Lim, logDt, Cst);
    gC<<<dim3(SL / 32, NB), 256, 0, stream>>>(u, Bhat, Chat, logLr, Lim, logDt,
                                              Cst, Dv, out);
}